// Round 1
// baseline (40.743 us; speedup 1.0000x reference)
//
#include <hip/hip_runtime.h>

// out[b,e,t] = sum_{s<=t} x[b,e,s] * (w0[s]*dv0^(t-s) + w1[t]*dv1^(t-s)) + bias[t]
// => two constant-coefficient linear recurrences per row:
//      P[t] = dv0*P[t-1] + x[t]*w0[t]
//      Q[t] = dv1*Q[t-1] + x[t]
//    out[t] = P[t] + w1[t]*Q[t] + bias[t]
// One wave (64 lanes) per row of length S=2048; 32 elements per lane.

#define S_LEN 2048
#define SEG 32               // elements per lane
#define WAVES_PER_BLOCK 4    // 256 threads, 4 rows per block

__global__ __launch_bounds__(256, 4)
void crcl_scan_kernel(const float* __restrict__ x,
                      const float* __restrict__ weight,
                      const float* __restrict__ bias,
                      const float* __restrict__ decay,
                      float* __restrict__ out,
                      int nrows)
{
    // 8 KiB per wave staging buffer, swizzled at float4 granularity.
    __shared__ float lds[WAVES_PER_BLOCK][S_LEN];   // 32 KiB / block

    const int wid  = (int)(threadIdx.x >> 6);
    const int lane = (int)(threadIdx.x & 63);
    long row = (long)blockIdx.x * WAVES_PER_BLOCK + wid;
    if (row >= nrows) row = nrows - 1;   // duplicate work (same values) keeps barriers uniform

    const float dv0 = fminf(fmaxf(decay[0], 0.9f), 1.0f);
    const float dv1 = fminf(fmaxf(decay[1], 0.9f), 1.0f);

    // ---- stage row into LDS, coalesced float4, XOR-swizzled ----
    float4* lds4 = (float4*)lds[wid];
    const float4* x4 = (const float4*)(x + row * (long)S_LEN);
#pragma unroll
    for (int it = 0; it < 8; ++it) {
        const int j = it * 64 + lane;
        lds4[j ^ ((j >> 3) & 7)] = x4[j];
    }
    __syncthreads();

    // ---- per-lane serial scan of 32 contiguous elements ----
    const float4* w0_4 = (const float4*)(weight);           // weight[0][:]
    float p[SEG], q[SEG];
    float pc = 0.0f, qc = 0.0f;
#pragma unroll
    for (int m = 0; m < 8; ++m) {
        const int j = 8 * lane + m;
        const float4 xv = lds4[j ^ ((j >> 3) & 7)];
        const float4 wv = w0_4[j];
        const float xs[4] = {xv.x, xv.y, xv.z, xv.w};
        const float ws[4] = {wv.x, wv.y, wv.z, wv.w};
#pragma unroll
        for (int t = 0; t < 4; ++t) {
            const int k = 4 * m + t;
            pc = fmaf(dv0, pc, xs[t] * ws[t]);
            qc = fmaf(dv1, qc, xs[t]);
            p[k] = pc;
            q[k] = qc;
        }
    }

    // ---- wave-level Kogge-Stone scan of segment carries ----
    // C_l = A * C_{l-1} + c_l, A = dv^SEG (constant) -> coef-squaring scan.
    float A0 = dv0 * dv0; A0 *= A0; A0 *= A0; A0 *= A0; A0 *= A0;  // dv0^32
    float A1 = dv1 * dv1; A1 *= A1; A1 *= A1; A1 *= A1; A1 *= A1;  // dv1^32

    float cp = pc, cq = qc;
    float k0 = A0, k1 = A1;
#pragma unroll
    for (int d = 1; d < 64; d <<= 1) {
        const float up_p = __shfl_up(cp, (unsigned)d, 64);
        const float up_q = __shfl_up(cq, (unsigned)d, 64);
        if (lane >= d) {
            cp = fmaf(k0, up_p, cp);
            cq = fmaf(k1, up_q, cq);
        }
        k0 *= k0;
        k1 *= k1;
    }
    float cin_p = __shfl_up(cp, 1u, 64);
    float cin_q = __shfl_up(cq, 1u, 64);
    if (lane == 0) { cin_p = 0.0f; cin_q = 0.0f; }

    // ---- fixup + combine + stage output (swizzled) ----
    const float4* w1_4 = (const float4*)(weight + S_LEN);   // weight[1][:]
    const float4* b_4  = (const float4*)bias;
    float pw0 = dv0, pw1 = dv1;   // dv^(k+1) for k = 0..31
#pragma unroll
    for (int m = 0; m < 8; ++m) {
        const int j = 8 * lane + m;
        const float4 wv = w1_4[j];
        const float4 bv = b_4[j];
        float4 yv;
        {
            const int k = 4 * m + 0;
            const float Pk = fmaf(cin_p, pw0, p[k]);
            const float Qk = fmaf(cin_q, pw1, q[k]);
            pw0 *= dv0; pw1 *= dv1;
            yv.x = fmaf(wv.x, Qk, Pk) + bv.x;
        }
        {
            const int k = 4 * m + 1;
            const float Pk = fmaf(cin_p, pw0, p[k]);
            const float Qk = fmaf(cin_q, pw1, q[k]);
            pw0 *= dv0; pw1 *= dv1;
            yv.y = fmaf(wv.y, Qk, Pk) + bv.y;
        }
        {
            const int k = 4 * m + 2;
            const float Pk = fmaf(cin_p, pw0, p[k]);
            const float Qk = fmaf(cin_q, pw1, q[k]);
            pw0 *= dv0; pw1 *= dv1;
            yv.z = fmaf(wv.z, Qk, Pk) + bv.z;
        }
        {
            const int k = 4 * m + 3;
            const float Pk = fmaf(cin_p, pw0, p[k]);
            const float Qk = fmaf(cin_q, pw1, q[k]);
            pw0 *= dv0; pw1 *= dv1;
            yv.w = fmaf(wv.w, Qk, Pk) + bv.w;
        }
        lds4[j ^ ((j >> 3) & 7)] = yv;
    }
    __syncthreads();

    // ---- coalesced float4 store ----
    float4* out4 = (float4*)(out + row * (long)S_LEN);
#pragma unroll
    for (int it = 0; it < 8; ++it) {
        const int j = it * 64 + lane;
        out4[j] = lds4[j ^ ((j >> 3) & 7)];
    }
}

extern "C" void kernel_launch(void* const* d_in, const int* in_sizes, int n_in,
                              void* d_out, int out_size, void* d_ws, size_t ws_size,
                              hipStream_t stream) {
    const float* x      = (const float*)d_in[0];
    const float* weight = (const float*)d_in[1];
    const float* bias   = (const float*)d_in[2];
    const float* decay  = (const float*)d_in[3];
    float* out = (float*)d_out;

    const int nrows   = in_sizes[0] / S_LEN;            // B*E = 8192
    const int nblocks = (nrows + WAVES_PER_BLOCK - 1) / WAVES_PER_BLOCK;

    hipLaunchKernelGGL(crcl_scan_kernel, dim3(nblocks), dim3(256), 0, stream,
                       x, weight, bias, decay, out, nrows);
}

// Round 2
// 26.649 us; speedup vs baseline: 1.5289x; 1.5289x over previous
//
#include <hip/hip_runtime.h>

// out[b,e,t] = sum_{s<=t} x[s]*(w0[s]*dv0^(t-s) + w1[t]*dv1^(t-s)) + bias[t]
//   P[t] = dv0*P[t-1] + x[t]*w0[t];  Q[t] = dv1*Q[t-1] + x[t]
//   out[t] = P[t] + w1[t]*Q[t] + bias[t]
// One row (S=2048) per 256-thread block: 8 elems/thread, wave shfl-scan,
// cross-wave carry combine, LDS-transposed coalesced I/O.

#define S_LEN 2048
#define EPT 8
#define THREADS 256

__device__ __forceinline__ int sw(int s) { return s ^ ((s >> 3) & 7); }  // f4-slot swizzle (involution)

typedef __attribute__((address_space(1))) const void g1void;
typedef __attribute__((address_space(3))) void l3void;

__global__ __launch_bounds__(THREADS, 8)
void crcl_kernel(const float* __restrict__ x,
                 const float* __restrict__ weight,
                 const float* __restrict__ bias,
                 const float* __restrict__ decay,
                 float* __restrict__ out)
{
    __shared__ float ldsrow[S_LEN];     // 8 KiB staging (in, then out)
    __shared__ float carry[2][4];       // per-wave totals [p/q][wave]

    const int t    = (int)threadIdx.x;
    const int lane = t & 63;
    const int w    = t >> 6;
    const long row = (long)blockIdx.x;

    const float dv0 = fminf(fmaxf(decay[0], 0.9f), 1.0f);
    const float dv1 = fminf(fmaxf(decay[1], 0.9f), 1.0f);

    // ---- stage x row -> LDS: linear LDS dest, pre-swizzled global source ----
    float4* lds4 = (float4*)ldsrow;
    const float4* x4 = (const float4*)(x + row * (long)S_LEN);
#pragma unroll
    for (int it = 0; it < 2; ++it) {
        const int s = it * 256 + t;                       // linear LDS f4 slot
        __builtin_amdgcn_global_load_lds((g1void*)&x4[sw(s)], (l3void*)&lds4[s],
                                         16, 0, 0);
    }
    __syncthreads();

    // ---- per-thread serial scan of 8 contiguous elements ----
    const float4* w0_4 = (const float4*)weight;           // weight[0][:]
    float p[EPT], q[EPT];
    float pc = 0.0f, qc = 0.0f;
#pragma unroll
    for (int c = 0; c < 2; ++c) {
        const int s = 2 * t + c;
        const float4 xv = lds4[sw(s)];
        const float4 wv = w0_4[s];
        const float xs[4] = {xv.x, xv.y, xv.z, xv.w};
        const float ws[4] = {wv.x, wv.y, wv.z, wv.w};
#pragma unroll
        for (int j = 0; j < 4; ++j) {
            const int k = 4 * c + j;
            pc = fmaf(dv0, pc, xs[j] * ws[j]);
            qc = fmaf(dv1, qc, xs[j]);
            p[k] = pc;
            q[k] = qc;
        }
    }

    // ---- wave Kogge-Stone scan of 8-elem segment carries (A = dv^8) ----
    float A8_0 = dv0 * dv0; A8_0 *= A8_0; A8_0 *= A8_0;   // dv0^8
    float A8_1 = dv1 * dv1; A8_1 *= A8_1; A8_1 *= A8_1;   // dv1^8

    float cp = pc, cq = qc;
    float k0 = A8_0, k1 = A8_1;
#pragma unroll
    for (int d = 1; d < 64; d <<= 1) {
        const float up = __shfl_up(cp, (unsigned)d, 64);
        const float uq = __shfl_up(cq, (unsigned)d, 64);
        if (lane >= d) {
            cp = fmaf(k0, up, cp);
            cq = fmaf(k1, uq, cq);
        }
        k0 *= k0;
        k1 *= k1;
    }
    float cin_p = __shfl_up(cp, 1u, 64);
    float cin_q = __shfl_up(cq, 1u, 64);
    if (lane == 0) { cin_p = 0.0f; cin_q = 0.0f; }

    // ---- cross-wave carry combine (A = dv^512) ----
    if (lane == 63) { carry[0][w] = cp; carry[1][w] = cq; }
    __syncthreads();

    float A512_0 = A8_0, A512_1 = A8_1;                   // ^64 via 6 squarings
#pragma unroll
    for (int b = 0; b < 6; ++b) { A512_0 *= A512_0; A512_1 *= A512_1; }

    float cwp = 0.0f, cwq = 0.0f;                         // carry into this wave
#pragma unroll
    for (int v = 0; v < 3; ++v) {
        if (v < w) {
            cwp = fmaf(cwp, A512_0, carry[0][v]);
            cwq = fmaf(cwq, A512_1, carry[1][v]);
        }
    }
    // fold wave carry into lane carry: + cw * dv^(8*lane)
    const float lf = (float)lane;
    const float pw8_0 = exp2f(lf * log2f(A8_0));
    const float pw8_1 = exp2f(lf * log2f(A8_1));
    cin_p = fmaf(cwp, pw8_0, cin_p);
    cin_q = fmaf(cwq, pw8_1, cin_q);

    // ---- fixup + combine + out-stage (swizzled) ----
    const float4* w1_4 = (const float4*)(weight + S_LEN); // weight[1][:]
    const float4* b_4  = (const float4*)bias;
    float pw0 = dv0, pw1 = dv1;                           // dv^(k+1), k=0..7
#pragma unroll
    for (int c = 0; c < 2; ++c) {
        const int s = 2 * t + c;
        const float4 wv = w1_4[s];
        const float4 bv = b_4[s];
        float yr[4];
#pragma unroll
        for (int j = 0; j < 4; ++j) {
            const int k = 4 * c + j;
            const float Pk = fmaf(cin_p, pw0, p[k]);
            const float Qk = fmaf(cin_q, pw1, q[k]);
            pw0 *= dv0; pw1 *= dv1;
            const float wj = (j == 0) ? wv.x : (j == 1) ? wv.y : (j == 2) ? wv.z : wv.w;
            const float bj = (j == 0) ? bv.x : (j == 1) ? bv.y : (j == 2) ? bv.z : bv.w;
            yr[j] = fmaf(wj, Qk, Pk) + bj;
        }
        lds4[sw(s)] = make_float4(yr[0], yr[1], yr[2], yr[3]);
    }
    __syncthreads();

    // ---- coalesced float4 store (read swizzled, store linear) ----
    float4* out4 = (float4*)(out + row * (long)S_LEN);
#pragma unroll
    for (int it = 0; it < 2; ++it) {
        const int s = it * 256 + t;
        out4[s] = lds4[sw(s)];
    }
}

extern "C" void kernel_launch(void* const* d_in, const int* in_sizes, int n_in,
                              void* d_out, int out_size, void* d_ws, size_t ws_size,
                              hipStream_t stream) {
    const float* x      = (const float*)d_in[0];
    const float* weight = (const float*)d_in[1];
    const float* bias   = (const float*)d_in[2];
    const float* decay  = (const float*)d_in[3];
    float* out = (float*)d_out;

    const int nrows = in_sizes[0] / S_LEN;   // B*E = 8192 rows, one block each
    hipLaunchKernelGGL(crcl_kernel, dim3(nrows), dim3(THREADS), 0, stream,
                       x, weight, bias, decay, out);
}